// Round 5
// baseline (55.629 us; speedup 1.0000x reference)
//
#include <hip/hip_runtime.h>
#include <hip/hip_bf16.h>

typedef __attribute__((ext_vector_type(8))) short bf16x8;
typedef __attribute__((ext_vector_type(4))) float f32x4;

#define T_DIM 4096
#define B_DIM 16
#define D_DIM 128
#define TILE 64
#define ROWS 96          // staged rows: t0-16 .. t0+79
#define SROW 136         // bf16 units per row (272 B, 16B-aligned)
#define NEGV -1e30f
#define NBLK 1024

__global__ __launch_bounds__(512, 6) void lcl_main(
    const float* __restrict__ mot, const float* __restrict__ aud,
    float* __restrict__ ws, unsigned* __restrict__ cnt,
    float* __restrict__ out)
{
    __shared__ unsigned short sm[ROWS * SROW];
    __shared__ unsigned short sa[ROWS * SROW];
    __shared__ float redL[8], redC[8];
    __shared__ unsigned sdone;

    const int tid  = threadIdx.x;
    const int lane = tid & 63;
    const int wv   = tid >> 6;     // 0..7
    const int g32  = tid >> 5;     // 0..15 staging group
    const int l32  = tid & 31;

    // XCD-aware bijective swizzle: blocks on the same XCD get consecutive bx
    // (shared halo rows -> same-XCD L2 hits). 1024 % 8 == 0 -> bijective.
    const int lin = blockIdx.y * gridDim.x + blockIdx.x;     // 0..1023
    const int swz = (lin & 7) * (NBLK / 8) + (lin >> 3);
    const int bx  = swz & 63;
    const int by  = swz >> 6;
    const int t0  = bx * TILE;
    const size_t base = (size_t)by * (T_DIM * D_DIM);

    // ---- stage: normalize (f32) -> bf16 into LDS, 96 rows per tensor ----
    auto stage = [&](const float* __restrict__ src,
                     unsigned short* __restrict__ dst, bool check) {
        const float* sp = src + base + (size_t)(t0 - 16 + g32) * D_DIM + l32 * 4;
        unsigned short* dp = dst + g32 * SROW + l32 * 4;
        #pragma unroll
        for (int i = 0; i < 6; ++i) {
            const int lr = g32 + 16 * i;
            float4 v = make_float4(0.f, 0.f, 0.f, 0.f);
            if (!check || ((unsigned)(t0 - 16 + lr) < (unsigned)T_DIM)) {
                v = *reinterpret_cast<const float4*>(sp + (size_t)(16 * i) * D_DIM);
            }
            float ss = v.x*v.x + v.y*v.y + v.z*v.z + v.w*v.w;
            #pragma unroll
            for (int m = 16; m; m >>= 1) ss += __shfl_xor(ss, m);
            const float inv = 1.0f / fmaxf(sqrtf(ss), 1e-12f);
            union { __hip_bfloat16 h[4]; uint2 u; } pk;
            pk.h[0] = __float2bfloat16(v.x * inv);
            pk.h[1] = __float2bfloat16(v.y * inv);
            pk.h[2] = __float2bfloat16(v.z * inv);
            pk.h[3] = __float2bfloat16(v.w * inv);
            *reinterpret_cast<uint2*>(dp + 16 * i * SROW) = pk.u;
        }
    };
    const bool interior = (t0 >= 16) && (t0 + 80 <= T_DIM);
    if (interior) { stage(mot, sm, false); stage(aud, sa, false); }
    else          { stage(mot, sm, true);  stage(aud, sa, true);  }
    __syncthreads();

    // ---- per-wave task: dir = wv>>2, mi = wv&3 ----
    const int dir = wv >> 2;
    const int mi  = wv & 3;
    const unsigned short* q = dir ? sa : sm;
    const unsigned short* k = dir ? sm : sa;

    const int fr  = lane & 15;          // fragment row/col
    const int fch = (lane >> 4) * 8;    // k-chunk (bf16 units)

    f32x4 acc0 = {0.f,0.f,0.f,0.f}, acc1 = acc0, acc2 = acc0;
    const unsigned short* qrow = q + (mi * 16 + 16 + fr) * SROW + fch;
    const unsigned short* k0   = k + ((mi + 0) * 16 + fr) * SROW + fch;
    const unsigned short* k1   = k + ((mi + 1) * 16 + fr) * SROW + fch;
    const unsigned short* k2   = k + ((mi + 2) * 16 + fr) * SROW + fch;
    #pragma unroll
    for (int ks = 0; ks < 4; ++ks) {
        bf16x8 af = *reinterpret_cast<const bf16x8*>(qrow + ks * 32);
        bf16x8 b0 = *reinterpret_cast<const bf16x8*>(k0   + ks * 32);
        bf16x8 b1 = *reinterpret_cast<const bf16x8*>(k1   + ks * 32);
        bf16x8 b2 = *reinterpret_cast<const bf16x8*>(k2   + ks * 32);
        acc0 = __builtin_amdgcn_mfma_f32_16x16x32_bf16(af, b0, acc0, 0, 0, 0);
        acc1 = __builtin_amdgcn_mfma_f32_16x16x32_bf16(af, b1, acc1, 0, 0, 0);
        acc2 = __builtin_amdgcn_mfma_f32_16x16x32_bf16(af, b2, acc2, 0, 0, 0);
    }

    // ---- in-register band reduction ----
    // C/D layout: col = lane&15, row = (lane>>4)*4 + reg.
    const int g     = lane >> 4;
    const int col16 = lane & 15;
    float lossW = 0.f, corrW = 0.f;
    #pragma unroll
    for (int r = 0; r < 4; ++r) {
        const int  crow = g * 4 + r;
        const int  kk0  = 16 + col16 - crow;
        const int  j0   = t0 + mi * 16 + col16;                 // a=1 key index
        const bool val0 = (j0 >= 0) && (j0 < T_DIM);
        const bool sel0 = (col16 >= crow);
        const float v1  = sel0 ? acc0[r] : acc2[r];
        const int  kk1  = sel0 ? (col16 - crow) : (32 + col16 - crow);
        const int  j1   = t0 - 16 + (mi + (sel0 ? 0 : 2)) * 16 + col16;
        const bool val1 = (j1 >= 0) && (j1 < T_DIM);
        const float l0  = val0 ? acc1[r] * 10.0f : NEGV;
        const float l1  = val1 ? v1      * 10.0f : NEGV;
        const float p0  = (val0 && kk0 >= 12 && kk0 < 20) ? l0 : NEGV;
        const float p1  = (val1 && kk1 >= 12 && kk1 < 20) ? l1 : NEGV;

        float mx  = fmaxf(l0, l1);
        float mxp = fmaxf(p0, p1);
        #pragma unroll
        for (int m = 8; m; m >>= 1) {
            mx  = fmaxf(mx,  __shfl_xor(mx,  m));
            mxp = fmaxf(mxp, __shfl_xor(mxp, m));
        }
        float s  = __expf(l0 - mx)  + __expf(l1 - mx);
        float sp = __expf(p0 - mxp) + __expf(p1 - mxp);
        #pragma unroll
        for (int m = 8; m; m >>= 1) {
            s  += __shfl_xor(s,  m);
            sp += __shfl_xor(sp, m);
        }
        if (col16 == 0) {
            lossW += (mx + __logf(s)) - (mxp + __logf(sp));
            corrW += (mxp >= mx) ? 1.0f : 0.0f;
        }
    }

    // wave partials at lanes 0,16,32,48 -> lane 0
    lossW += __shfl_xor(lossW, 16);
    corrW += __shfl_xor(corrW, 16);
    lossW += __shfl_xor(lossW, 32);
    corrW += __shfl_xor(corrW, 32);
    if (lane == 0) { redL[wv] = lossW; redC[wv] = corrW; }
    __syncthreads();
    if (tid == 0) {
        float L = 0.f, C = 0.f;
        #pragma unroll
        for (int i = 0; i < 8; ++i) { L += redL[i]; C += redC[i]; }
        ws[2 * swz]     = L;
        ws[2 * swz + 1] = C;
        __threadfence();                       // make partials device-visible
        const unsigned prev = atomicAdd(cnt, 1u);
        sdone = (prev == NBLK - 1) ? 1u : 0u;
    }
    __syncthreads();

    // ---- last block finalizes (fixed summation order -> deterministic) ----
    if (sdone) {
        __threadfence();                       // acquire others' partials
        float L = 0.f, C = 0.f;
        #pragma unroll
        for (int i = 0; i < 2; ++i) {
            const int idx = tid + i * 512;
            L += ws[2 * idx];
            C += ws[2 * idx + 1];
        }
        #pragma unroll
        for (int m = 32; m; m >>= 1) {
            L += __shfl_xor(L, m);
            C += __shfl_xor(C, m);
        }
        if (lane == 0) { redL[wv] = L; redC[wv] = C; }
        __syncthreads();
        if (tid == 0) {
            float Lt = 0.f, Ct = 0.f;
            #pragma unroll
            for (int i = 0; i < 8; ++i) { Lt += redL[i]; Ct += redC[i]; }
            out[0] = Lt * (1.0f / 131072.0f);  // / (B * 2T)
            out[1] = Ct * (1.0f / 131072.0f);  // / (2 * T * B)
        }
    }
}

extern "C" void kernel_launch(void* const* d_in, const int* in_sizes, int n_in,
                              void* d_out, int out_size, void* d_ws, size_t ws_size,
                              hipStream_t stream) {
    const float* mot = (const float*)d_in[0];
    const float* aud = (const float*)d_in[1];
    float* out = (float*)d_out;
    float* ws  = (float*)d_ws;                       // 1024 x 2 floats
    unsigned* cnt = (unsigned*)(ws + 2 * NBLK);      // completion counter

    (void)hipMemsetAsync(cnt, 0, sizeof(unsigned), stream);  // graph-capturable
    dim3 grid(T_DIM / TILE, B_DIM);
    lcl_main<<<grid, 512, 0, stream>>>(mot, aud, ws, cnt, out);
}

// Round 6
// 51.569 us; speedup vs baseline: 1.0787x; 1.0787x over previous
//
#include <hip/hip_runtime.h>
#include <hip/hip_bf16.h>

typedef __attribute__((ext_vector_type(8))) short bf16x8;
typedef __attribute__((ext_vector_type(4))) float f32x4;

#define T_DIM 4096
#define B_DIM 16
#define D_DIM 128
#define TILE 64
#define ROWS 96          // staged rows: t0-16 .. t0+79
#define SROW 136         // bf16 units per row (272 B, 16B-aligned)
#define NEGV -1e30f
#define NBLK 1024
#define SCALE (1.0f / 131072.0f)   // 1 / (B * 2T)

__global__ __launch_bounds__(512, 6) void lcl_main(
    const float* __restrict__ mot, const float* __restrict__ aud,
    float* __restrict__ out)
{
    __shared__ unsigned short sm[ROWS * SROW];
    __shared__ unsigned short sa[ROWS * SROW];
    __shared__ float redL[8], redC[8];

    const int tid  = threadIdx.x;
    const int lane = tid & 63;
    const int wv   = tid >> 6;     // 0..7
    const int g32  = tid >> 5;     // 0..15 staging group
    const int l32  = tid & 31;

    // XCD-aware bijective swizzle: same-XCD blocks get consecutive bx
    // (shared halo rows -> same-XCD L2 hits). 1024 % 8 == 0 -> bijective.
    const int lin = blockIdx.y * gridDim.x + blockIdx.x;     // 0..1023
    const int swz = (lin & 7) * (NBLK / 8) + (lin >> 3);
    const int bx  = swz & 63;
    const int by  = swz >> 6;
    const int t0  = bx * TILE;
    const size_t base = (size_t)by * (T_DIM * D_DIM);

    // ---- stage: normalize (f32) -> bf16 into LDS, both tensors interleaved ----
    {
        const size_t off = base + (size_t)(t0 - 16 + g32) * D_DIM + l32 * 4;
        const float* spm = mot + off;
        const float* spa = aud + off;
        unsigned short* dpm = sm + g32 * SROW + l32 * 4;
        unsigned short* dpa = sa + g32 * SROW + l32 * 4;
        const bool interior = (t0 >= 16) && (t0 + 80 <= T_DIM);

        #pragma unroll
        for (int i = 0; i < 6; ++i) {
            const int lr = g32 + 16 * i;
            float4 vm = make_float4(0.f, 0.f, 0.f, 0.f);
            float4 va = vm;
            const bool ok = interior || ((unsigned)(t0 - 16 + lr) < (unsigned)T_DIM);
            if (ok) {
                vm = *reinterpret_cast<const float4*>(spm + (size_t)(16 * i) * D_DIM);
                va = *reinterpret_cast<const float4*>(spa + (size_t)(16 * i) * D_DIM);
            }
            float sqm = vm.x*vm.x + vm.y*vm.y + vm.z*vm.z + vm.w*vm.w;
            float sqa = va.x*va.x + va.y*va.y + va.z*va.z + va.w*va.w;
            #pragma unroll
            for (int m = 16; m; m >>= 1) {
                sqm += __shfl_xor(sqm, m);
                sqa += __shfl_xor(sqa, m);
            }
            const float invm = 1.0f / fmaxf(sqrtf(sqm), 1e-12f);
            const float inva = 1.0f / fmaxf(sqrtf(sqa), 1e-12f);
            union { __hip_bfloat16 h[4]; uint2 u; } pm, pa;
            pm.h[0] = __float2bfloat16(vm.x * invm);
            pm.h[1] = __float2bfloat16(vm.y * invm);
            pm.h[2] = __float2bfloat16(vm.z * invm);
            pm.h[3] = __float2bfloat16(vm.w * invm);
            pa.h[0] = __float2bfloat16(va.x * inva);
            pa.h[1] = __float2bfloat16(va.y * inva);
            pa.h[2] = __float2bfloat16(va.z * inva);
            pa.h[3] = __float2bfloat16(va.w * inva);
            *reinterpret_cast<uint2*>(dpm + 16 * i * SROW) = pm.u;
            *reinterpret_cast<uint2*>(dpa + 16 * i * SROW) = pa.u;
        }
    }
    __syncthreads();

    // ---- per-wave task: dir = wv>>2, mi = wv&3 ----
    const int dir = wv >> 2;
    const int mi  = wv & 3;
    const unsigned short* q = dir ? sa : sm;
    const unsigned short* k = dir ? sm : sa;

    const int fr  = lane & 15;          // fragment row/col
    const int fch = (lane >> 4) * 8;    // k-chunk (bf16 units)

    f32x4 acc0 = {0.f,0.f,0.f,0.f}, acc1 = acc0, acc2 = acc0;
    const unsigned short* qrow = q + (mi * 16 + 16 + fr) * SROW + fch;
    const unsigned short* k0   = k + ((mi + 0) * 16 + fr) * SROW + fch;
    const unsigned short* k1   = k + ((mi + 1) * 16 + fr) * SROW + fch;
    const unsigned short* k2   = k + ((mi + 2) * 16 + fr) * SROW + fch;
    #pragma unroll
    for (int ks = 0; ks < 4; ++ks) {
        bf16x8 af = *reinterpret_cast<const bf16x8*>(qrow + ks * 32);
        bf16x8 b0 = *reinterpret_cast<const bf16x8*>(k0   + ks * 32);
        bf16x8 b1 = *reinterpret_cast<const bf16x8*>(k1   + ks * 32);
        bf16x8 b2 = *reinterpret_cast<const bf16x8*>(k2   + ks * 32);
        acc0 = __builtin_amdgcn_mfma_f32_16x16x32_bf16(af, b0, acc0, 0, 0, 0);
        acc1 = __builtin_amdgcn_mfma_f32_16x16x32_bf16(af, b1, acc1, 0, 0, 0);
        acc2 = __builtin_amdgcn_mfma_f32_16x16x32_bf16(af, b2, acc2, 0, 0, 0);
    }

    // ---- in-register band reduction ----
    // C/D layout: col = lane&15, row = (lane>>4)*4 + reg.
    // Band member kk = a*16 + col16 - crow (kk in [0,32)).
    //   a=1 always in band; j0 = t0+mi*16+col16 is provably in [0,T) -> no check.
    //   a=0 iff col16>=crow else a=2; j1 needs the bounds check.
    const int g     = lane >> 4;
    const int col16 = lane & 15;
    float lossW = 0.f, corrW = 0.f;
    #pragma unroll
    for (int r = 0; r < 4; ++r) {
        const int  crow = g * 4 + r;
        const int  kk0  = 16 + col16 - crow;
        const bool sel0 = (col16 >= crow);
        const float v1  = sel0 ? acc0[r] : acc2[r];
        const int  kk1  = sel0 ? (col16 - crow) : (32 + col16 - crow);
        const int  j1   = t0 - 16 + (mi + (sel0 ? 0 : 2)) * 16 + col16;
        const bool val1 = (unsigned)j1 < (unsigned)T_DIM;
        const float l0  = acc1[r] * 10.0f;
        const float l1  = val1 ? v1 * 10.0f : NEGV;
        const float p0  = ((unsigned)(kk0 - 12) < 8u) ? l0 : NEGV;
        const float p1  = ((unsigned)(kk1 - 12) < 8u) ? l1 : NEGV;

        float mx  = fmaxf(l0, l1);
        float mxp = fmaxf(p0, p1);
        #pragma unroll
        for (int m = 8; m; m >>= 1) {
            mx  = fmaxf(mx,  __shfl_xor(mx,  m));
            mxp = fmaxf(mxp, __shfl_xor(mxp, m));
        }
        float s  = __expf(l0 - mx)  + __expf(l1 - mx);
        float sp = __expf(p0 - mxp) + __expf(p1 - mxp);
        #pragma unroll
        for (int m = 8; m; m >>= 1) {
            s  += __shfl_xor(s,  m);
            sp += __shfl_xor(sp, m);
        }
        if (col16 == 0) {
            lossW += (mx + __logf(s)) - (mxp + __logf(sp));
            corrW += (mxp >= mx) ? 1.0f : 0.0f;
        }
    }

    // wave partials at lanes 0,16,32,48 -> lane 0
    lossW += __shfl_xor(lossW, 16);
    corrW += __shfl_xor(corrW, 16);
    lossW += __shfl_xor(lossW, 32);
    corrW += __shfl_xor(corrW, 32);
    if (lane == 0) { redL[wv] = lossW; redC[wv] = corrW; }
    __syncthreads();
    if (tid == 0) {
        float L = 0.f, C = 0.f;
        #pragma unroll
        for (int i = 0; i < 8; ++i) { L += redL[i]; C += redC[i]; }
        // Fire-and-forget device-scope float atomics; no fence, no 2nd kernel.
        // C*SCALE terms are exact multiples of 2^-17 -> bit-deterministic sum.
        atomicAdd(&out[0], L * SCALE);
        atomicAdd(&out[1], C * SCALE);
    }
}

extern "C" void kernel_launch(void* const* d_in, const int* in_sizes, int n_in,
                              void* d_out, int out_size, void* d_ws, size_t ws_size,
                              hipStream_t stream) {
    const float* mot = (const float*)d_in[0];
    const float* aud = (const float*)d_in[1];
    float* out = (float*)d_out;

    (void)hipMemsetAsync(out, 0, 2 * sizeof(float), stream);  // graph-capturable
    dim3 grid(T_DIM / TILE, B_DIM);
    lcl_main<<<grid, 512, 0, stream>>>(mot, aud, out);
}

// Round 7
// 49.368 us; speedup vs baseline: 1.1268x; 1.0446x over previous
//
#include <hip/hip_runtime.h>
#include <hip/hip_bf16.h>

typedef __attribute__((ext_vector_type(8))) short bf16x8;
typedef __attribute__((ext_vector_type(4))) float f32x4;

#define T_DIM 4096
#define B_DIM 16
#define D_DIM 128
#define TILE 64
#define ROWS 96          // staged rows: t0-16 .. t0+79
#define SROW 136         // bf16 units per row (272 B, 16B-aligned)
#define NEGV -1e30f
#define SCALE (1.0f / 131072.0f)   // 1 / (B * 2T)

__global__ __launch_bounds__(512, 6) void lcl_main(
    const float* __restrict__ mot, const float* __restrict__ aud,
    float* __restrict__ out)
{
    __shared__ unsigned short sm[ROWS * SROW];
    __shared__ unsigned short sa[ROWS * SROW];
    __shared__ float invM[ROWS], invA[ROWS];   // inv row norms (bf16-consistent)
    __shared__ float redL[8], redC[8];

    const int tid  = threadIdx.x;
    const int lane = tid & 63;
    const int wv   = tid >> 6;     // 0..7
    const int g32  = tid >> 5;     // 0..15 staging group
    const int l32  = tid & 31;

    const int t0 = blockIdx.x * TILE;
    const size_t base = (size_t)blockIdx.y * (T_DIM * D_DIM);

    // ---- stage RAW bf16 (no normalize -> no cross-lane chains) ----
    {
        const size_t off = base + (size_t)(t0 - 16 + g32) * D_DIM + l32 * 4;
        float4 v[6];

        // motion: issue 6 loads, then convert+store
        const float* sp = mot + off;
        unsigned short* dp = sm + g32 * SROW + l32 * 4;
        #pragma unroll
        for (int i = 0; i < 6; ++i) {
            v[i] = make_float4(0.f, 0.f, 0.f, 0.f);
            if ((unsigned)(t0 - 16 + g32 + 16 * i) < (unsigned)T_DIM)
                v[i] = *reinterpret_cast<const float4*>(sp + (size_t)(16 * i) * D_DIM);
        }
        #pragma unroll
        for (int i = 0; i < 6; ++i) {
            union { __hip_bfloat16 h[4]; uint2 u; } p;
            p.h[0] = __float2bfloat16(v[i].x);
            p.h[1] = __float2bfloat16(v[i].y);
            p.h[2] = __float2bfloat16(v[i].z);
            p.h[3] = __float2bfloat16(v[i].w);
            *reinterpret_cast<uint2*>(dp + 16 * i * SROW) = p.u;
        }

        // audio
        const float* sp2 = aud + off;
        unsigned short* dp2 = sa + g32 * SROW + l32 * 4;
        #pragma unroll
        for (int i = 0; i < 6; ++i) {
            v[i] = make_float4(0.f, 0.f, 0.f, 0.f);
            if ((unsigned)(t0 - 16 + g32 + 16 * i) < (unsigned)T_DIM)
                v[i] = *reinterpret_cast<const float4*>(sp2 + (size_t)(16 * i) * D_DIM);
        }
        #pragma unroll
        for (int i = 0; i < 6; ++i) {
            union { __hip_bfloat16 h[4]; uint2 u; } p;
            p.h[0] = __float2bfloat16(v[i].x);
            p.h[1] = __float2bfloat16(v[i].y);
            p.h[2] = __float2bfloat16(v[i].z);
            p.h[3] = __float2bfloat16(v[i].w);
            *reinterpret_cast<uint2*>(dp2 + 16 * i * SROW) = p.u;
        }
    }
    __syncthreads();

    // ---- per-wave task: dir = wv>>2, mi = wv&3 ----
    const int dir = wv >> 2;
    const int mi  = wv & 3;
    const unsigned short* q = dir ? sa : sm;
    const unsigned short* k = dir ? sm : sa;
    float* invKarr = dir ? invM : invA;        // this wave's k-tensor norms

    const int fr  = lane & 15;
    const int fch = (lane >> 4) * 8;

    // SWAPPED MFMA: A = k rows, B = q rows  ->  C[row=k_jj][col=q_t]
    // Norm self-Grams reuse the already-loaded A fragments (0 extra ds_reads).
    f32x4 acc0 = {0.f,0.f,0.f,0.f}, acc1 = acc0, acc2 = acc0;
    f32x4 n0 = acc0, n1 = acc0;
    const unsigned short* qrow = q + (16 * (mi + 1) + fr) * SROW + fch;
    const unsigned short* k0   = k + ((mi + 0) * 16 + fr) * SROW + fch;
    const unsigned short* k1   = k + ((mi + 1) * 16 + fr) * SROW + fch;
    const unsigned short* k2   = k + ((mi + 2) * 16 + fr) * SROW + fch;
    #pragma unroll
    for (int ks = 0; ks < 4; ++ks) {
        bf16x8 bq = *reinterpret_cast<const bf16x8*>(qrow + ks * 32);
        bf16x8 a0 = *reinterpret_cast<const bf16x8*>(k0   + ks * 32);
        bf16x8 a1 = *reinterpret_cast<const bf16x8*>(k1   + ks * 32);
        bf16x8 a2 = *reinterpret_cast<const bf16x8*>(k2   + ks * 32);
        acc0 = __builtin_amdgcn_mfma_f32_16x16x32_bf16(a0, bq, acc0, 0, 0, 0);
        acc1 = __builtin_amdgcn_mfma_f32_16x16x32_bf16(a1, bq, acc1, 0, 0, 0);
        acc2 = __builtin_amdgcn_mfma_f32_16x16x32_bf16(a2, bq, acc2, 0, 0, 0);
        n0   = __builtin_amdgcn_mfma_f32_16x16x32_bf16(a0, a0, n0, 0, 0, 0);
        if (mi >= 2)
            n1 = __builtin_amdgcn_mfma_f32_16x16x32_bf16(a2, a2, n1, 0, 0, 0);
    }

    // ---- extract Gram diagonals -> inv norms (coverage: blocks 0..5 both tensors)
    const int col16 = lane & 15;
    const int g     = lane >> 4;
    if ((col16 >> 2) == g) {
        const int r = col16 & 3;
        invKarr[16 * mi + col16] = 1.0f / fmaxf(sqrtf(n0[r]), 1e-12f);
        if (mi >= 2)
            invKarr[16 * (mi + 2) + col16] = 1.0f / fmaxf(sqrtf(n1[r]), 1e-12f);
    }
    __syncthreads();

    // ---- band reduction: lane owns q-row t=col16; regs hold k values ----
    const float* invQarr = dir ? invA : invM;
    const float scq10 = 10.0f * invQarr[16 * (mi + 1) + col16];
    const f32x4 sck0 = *reinterpret_cast<const f32x4*>(&invKarr[16 * (mi + 0) + 4 * g]);
    const f32x4 sck1 = *reinterpret_cast<const f32x4*>(&invKarr[16 * (mi + 1) + 4 * g]);
    const f32x4 sck2 = *reinterpret_cast<const f32x4*>(&invKarr[16 * (mi + 2) + 4 * g]);

    const int jbase  = t0 - 16 + 16 * mi + 4 * g;   // + 16b + r = global key idx
    const int kkbase = 4 * g - col16;               // + 16b + r = kk in [0,32)

    float lv[12], pv[12];
    float mx = NEGV, mxp = NEGV;
    #pragma unroll
    for (int bb = 0; bb < 3; ++bb) {
        const f32x4 acc = (bb == 0) ? acc0 : ((bb == 1) ? acc1 : acc2);
        const f32x4 sck = (bb == 0) ? sck0 : ((bb == 1) ? sck1 : sck2);
        #pragma unroll
        for (int r = 0; r < 4; ++r) {
            const int kk = kkbase + 16 * bb + r;
            const int jg = jbase  + 16 * bb + r;
            const bool ok = ((unsigned)kk < 32u) && ((unsigned)jg < (unsigned)T_DIM);
            const float li = ok ? acc[r] * (scq10 * sck[r]) : NEGV;
            const float pi = ((unsigned)(kk - 12) < 8u) ? li : NEGV;
            lv[bb * 4 + r] = li;
            pv[bb * 4 + r] = pi;
            mx  = fmaxf(mx,  li);
            mxp = fmaxf(mxp, pi);
        }
    }
    mx  = fmaxf(mx,  __shfl_xor(mx,  16));
    mx  = fmaxf(mx,  __shfl_xor(mx,  32));
    mxp = fmaxf(mxp, __shfl_xor(mxp, 16));
    mxp = fmaxf(mxp, __shfl_xor(mxp, 32));

    float s = 0.f, sp = 0.f;
    #pragma unroll
    for (int i = 0; i < 12; ++i) {
        s  += __expf(lv[i] - mx);    // NEGV entries -> 0
        sp += __expf(pv[i] - mxp);
    }
    s  += __shfl_xor(s,  16);  s  += __shfl_xor(s,  32);
    sp += __shfl_xor(sp, 16);  sp += __shfl_xor(sp, 32);

    float lossW = 0.f, corrW = 0.f;
    if (g == 0) {                    // lanes 0..15: one q-row each
        lossW = (mx + __logf(s)) - (mxp + __logf(sp));
        corrW = (mxp >= mx) ? 1.0f : 0.0f;
    }

    // ---- block reduction + fire-and-forget atomics ----
    #pragma unroll
    for (int m = 32; m; m >>= 1) {
        lossW += __shfl_xor(lossW, m);
        corrW += __shfl_xor(corrW, m);
    }
    if (lane == 0) { redL[wv] = lossW; redC[wv] = corrW; }
    __syncthreads();
    if (tid == 0) {
        float L = 0.f, C = 0.f;
        #pragma unroll
        for (int i = 0; i < 8; ++i) { L += redL[i]; C += redC[i]; }
        atomicAdd(&out[0], L * SCALE);
        atomicAdd(&out[1], C * SCALE);
    }
}

extern "C" void kernel_launch(void* const* d_in, const int* in_sizes, int n_in,
                              void* d_out, int out_size, void* d_ws, size_t ws_size,
                              hipStream_t stream) {
    const float* mot = (const float*)d_in[0];
    const float* aud = (const float*)d_in[1];
    float* out = (float*)d_out;

    (void)hipMemsetAsync(out, 0, 2 * sizeof(float), stream);  // graph-capturable
    dim3 grid(T_DIM / TILE, B_DIM);
    lcl_main<<<grid, 512, 0, stream>>>(mot, aud, out);
}

// Round 8
// 24.883 us; speedup vs baseline: 2.2356x; 1.9840x over previous
//
#include <hip/hip_runtime.h>
#include <hip/hip_bf16.h>

typedef __attribute__((ext_vector_type(8))) short bf16x8;
typedef __attribute__((ext_vector_type(4))) float f32x4;

#define T_DIM 4096
#define B_DIM 16
#define D_DIM 128
#define TILE 64
#define ROWS 96          // staged rows: t0-16 .. t0+79
#define SROW 136         // bf16 units per row (272 B, 16B-aligned)
#define NEGV -1e30f
#define NBLK 1024
#define SCALE (1.0f / 131072.0f)   // 1 / (B * 2T)

__global__ __launch_bounds__(512, 4) void lcl_main(
    const float* __restrict__ mot, const float* __restrict__ aud,
    float* __restrict__ ws)
{
    __shared__ unsigned short sm[ROWS * SROW];
    __shared__ unsigned short sa[ROWS * SROW];
    __shared__ float invM[ROWS], invA[ROWS];   // inv row norms (of bf16 rows)
    __shared__ float redL[8], redC[8];

    const int tid  = threadIdx.x;
    const int lane = tid & 63;
    const int wv   = tid >> 6;     // 0..7
    const int g32  = tid >> 5;     // 0..15 staging group
    const int l32  = tid & 31;

    // XCD-aware bijective swizzle (1024 % 8 == 0): same-XCD blocks share halos.
    const int lin = blockIdx.y * gridDim.x + blockIdx.x;     // 0..1023
    const int swz = (lin & 7) * (NBLK / 8) + (lin >> 3);
    const int bx  = swz & 63;
    const int by  = swz >> 6;
    const int t0  = bx * TILE;
    const size_t base = (size_t)by * (T_DIM * D_DIM);

    // ---- stage RAW bf16: issue ALL 12 loads first, then convert+write ----
    {
        const size_t off = base + (size_t)(t0 - 16 + g32) * D_DIM + l32 * 4;
        const float* spm = mot + off;
        const float* spa = aud + off;
        float4 vm[6], va[6];
        #pragma unroll
        for (int i = 0; i < 6; ++i) {
            const bool ok = (unsigned)(t0 - 16 + g32 + 16 * i) < (unsigned)T_DIM;
            vm[i] = make_float4(0.f, 0.f, 0.f, 0.f);
            va[i] = vm[i];
            if (ok) {
                vm[i] = *reinterpret_cast<const float4*>(spm + (size_t)(16 * i) * D_DIM);
                va[i] = *reinterpret_cast<const float4*>(spa + (size_t)(16 * i) * D_DIM);
            }
        }
        unsigned short* dpm = sm + g32 * SROW + l32 * 4;
        unsigned short* dpa = sa + g32 * SROW + l32 * 4;
        #pragma unroll
        for (int i = 0; i < 6; ++i) {
            union { __hip_bfloat16 h[4]; uint2 u; } pm, pa;
            pm.h[0] = __float2bfloat16(vm[i].x);
            pm.h[1] = __float2bfloat16(vm[i].y);
            pm.h[2] = __float2bfloat16(vm[i].z);
            pm.h[3] = __float2bfloat16(vm[i].w);
            pa.h[0] = __float2bfloat16(va[i].x);
            pa.h[1] = __float2bfloat16(va[i].y);
            pa.h[2] = __float2bfloat16(va[i].z);
            pa.h[3] = __float2bfloat16(va[i].w);
            *reinterpret_cast<uint2*>(dpm + 16 * i * SROW) = pm.u;
            *reinterpret_cast<uint2*>(dpa + 16 * i * SROW) = pa.u;
        }
    }
    __syncthreads();

    // ---- per-wave task: dir = wv>>2, mi = wv&3 ----
    const int dir = wv >> 2;
    const int mi  = wv & 3;
    const unsigned short* q = dir ? sa : sm;
    const unsigned short* k = dir ? sm : sa;
    float* invKarr = dir ? invM : invA;        // this wave's k-tensor norms

    const int fr  = lane & 15;
    const int fch = (lane >> 4) * 8;

    // SWAPPED MFMA: A = k rows, B = q rows  ->  C[row=k_jj][col=q_t]
    // Norm self-Grams reuse the already-loaded A fragments (0 extra ds_reads).
    f32x4 acc0 = {0.f,0.f,0.f,0.f}, acc1 = acc0, acc2 = acc0;
    f32x4 n0 = acc0, n1 = acc0;
    const unsigned short* qrow = q + (16 * (mi + 1) + fr) * SROW + fch;
    const unsigned short* k0   = k + ((mi + 0) * 16 + fr) * SROW + fch;
    const unsigned short* k1   = k + ((mi + 1) * 16 + fr) * SROW + fch;
    const unsigned short* k2   = k + ((mi + 2) * 16 + fr) * SROW + fch;
    #pragma unroll
    for (int ks = 0; ks < 4; ++ks) {
        bf16x8 bq = *reinterpret_cast<const bf16x8*>(qrow + ks * 32);
        bf16x8 a0 = *reinterpret_cast<const bf16x8*>(k0   + ks * 32);
        bf16x8 a1 = *reinterpret_cast<const bf16x8*>(k1   + ks * 32);
        bf16x8 a2 = *reinterpret_cast<const bf16x8*>(k2   + ks * 32);
        acc0 = __builtin_amdgcn_mfma_f32_16x16x32_bf16(a0, bq, acc0, 0, 0, 0);
        acc1 = __builtin_amdgcn_mfma_f32_16x16x32_bf16(a1, bq, acc1, 0, 0, 0);
        acc2 = __builtin_amdgcn_mfma_f32_16x16x32_bf16(a2, bq, acc2, 0, 0, 0);
        n0   = __builtin_amdgcn_mfma_f32_16x16x32_bf16(a0, a0, n0, 0, 0, 0);
        if (mi >= 2)
            n1 = __builtin_amdgcn_mfma_f32_16x16x32_bf16(a2, a2, n1, 0, 0, 0);
    }

    // ---- Gram diagonals -> inv norms (blocks 0..5 covered for both tensors)
    const int col16 = lane & 15;
    const int g     = lane >> 4;
    if ((col16 >> 2) == g) {
        const int r = col16 & 3;
        invKarr[16 * mi + col16] = 1.0f / fmaxf(sqrtf(n0[r]), 1e-12f);
        if (mi >= 2)
            invKarr[16 * (mi + 2) + col16] = 1.0f / fmaxf(sqrtf(n1[r]), 1e-12f);
    }
    __syncthreads();

    // ---- band reduction: lane owns q-row t=col16; regs hold k values ----
    const float* invQarr = dir ? invA : invM;
    const float scq10 = 10.0f * invQarr[16 * (mi + 1) + col16];
    const f32x4 sck0 = *reinterpret_cast<const f32x4*>(&invKarr[16 * (mi + 0) + 4 * g]);
    const f32x4 sck1 = *reinterpret_cast<const f32x4*>(&invKarr[16 * (mi + 1) + 4 * g]);
    const f32x4 sck2 = *reinterpret_cast<const f32x4*>(&invKarr[16 * (mi + 2) + 4 * g]);

    const int jbase  = t0 - 16 + 16 * mi + 4 * g;   // + 16b + r = global key idx
    const int kkbase = 4 * g - col16;               // + 16b + r = kk in [0,32)

    float lv[12], pv[12];
    float mx = NEGV, mxp = NEGV;
    #pragma unroll
    for (int bb = 0; bb < 3; ++bb) {
        const f32x4 acc = (bb == 0) ? acc0 : ((bb == 1) ? acc1 : acc2);
        const f32x4 sck = (bb == 0) ? sck0 : ((bb == 1) ? sck1 : sck2);
        #pragma unroll
        for (int r = 0; r < 4; ++r) {
            const int kk = kkbase + 16 * bb + r;
            const int jg = jbase  + 16 * bb + r;
            const bool ok = ((unsigned)kk < 32u) && ((unsigned)jg < (unsigned)T_DIM);
            const float li = ok ? acc[r] * (scq10 * sck[r]) : NEGV;
            const float pi = ((unsigned)(kk - 12) < 8u) ? li : NEGV;
            lv[bb * 4 + r] = li;
            pv[bb * 4 + r] = pi;
            mx  = fmaxf(mx,  li);
            mxp = fmaxf(mxp, pi);
        }
    }
    mx  = fmaxf(mx,  __shfl_xor(mx,  16));
    mx  = fmaxf(mx,  __shfl_xor(mx,  32));
    mxp = fmaxf(mxp, __shfl_xor(mxp, 16));
    mxp = fmaxf(mxp, __shfl_xor(mxp, 32));

    float s = 0.f, sp = 0.f;
    #pragma unroll
    for (int i = 0; i < 12; ++i) {
        s  += __expf(lv[i] - mx);    // NEGV entries -> 0
        sp += __expf(pv[i] - mxp);
    }
    s  += __shfl_xor(s,  16);  s  += __shfl_xor(s,  32);
    sp += __shfl_xor(sp, 16);  sp += __shfl_xor(sp, 32);

    float lossW = 0.f, corrW = 0.f;
    if (g == 0) {                    // lanes 0..15: one q-row each
        lossW = (mx + __logf(s)) - (mxp + __logf(sp));
        corrW = (mxp >= mx) ? 1.0f : 0.0f;
    }

    // ---- block reduction -> per-block partials in ws (no atomics, no fence)
    #pragma unroll
    for (int m = 32; m; m >>= 1) {
        lossW += __shfl_xor(lossW, m);
        corrW += __shfl_xor(corrW, m);
    }
    if (lane == 0) { redL[wv] = lossW; redC[wv] = corrW; }
    __syncthreads();
    if (tid == 0) {
        float L = 0.f, C = 0.f;
        #pragma unroll
        for (int i = 0; i < 8; ++i) { L += redL[i]; C += redC[i]; }
        ws[2 * swz]     = L;
        ws[2 * swz + 1] = C;
    }
}

__global__ __launch_bounds__(256) void lcl_final(
    const float* __restrict__ ws, float* __restrict__ out)
{
    const int tid = threadIdx.x;
    float L = 0.f, C = 0.f;
    #pragma unroll
    for (int i = 0; i < 4; ++i) {
        const int idx = tid + i * 256;
        L += ws[2 * idx];
        C += ws[2 * idx + 1];
    }
    #pragma unroll
    for (int m = 32; m; m >>= 1) { L += __shfl_xor(L, m); C += __shfl_xor(C, m); }
    __shared__ float rl[4], rc[4];
    if ((tid & 63) == 0) { rl[tid >> 6] = L; rc[tid >> 6] = C; }
    __syncthreads();
    if (tid == 0) {
        out[0] = (rl[0] + rl[1] + rl[2] + rl[3]) * SCALE;
        out[1] = (rc[0] + rc[1] + rc[2] + rc[3]) * SCALE;
    }
}

extern "C" void kernel_launch(void* const* d_in, const int* in_sizes, int n_in,
                              void* d_out, int out_size, void* d_ws, size_t ws_size,
                              hipStream_t stream) {
    const float* mot = (const float*)d_in[0];
    const float* aud = (const float*)d_in[1];
    float* out = (float*)d_out;
    float* ws  = (float*)d_ws;   // 1024 blocks x 2 floats, fully overwritten

    dim3 grid(T_DIM / TILE, B_DIM);
    lcl_main<<<grid, 512, 0, stream>>>(mot, aud, ws);
    lcl_final<<<1, 256, 0, stream>>>(ws, out);
}

// Round 9
// 24.220 us; speedup vs baseline: 2.2968x; 1.0274x over previous
//
#include <hip/hip_runtime.h>
#include <hip/hip_bf16.h>

typedef __attribute__((ext_vector_type(8))) short bf16x8;
typedef __attribute__((ext_vector_type(4))) float f32x4;

#define T_DIM 4096
#define B_DIM 16
#define D_DIM 128
#define TILE 64
#define NTILE 2          // tiles per block (pipelined)
#define ROWS 96          // staged rows per tile: t0-16 .. t0+79
#define SROW 136         // bf16 units per row (272 B, 16B-aligned)
#define NEGV -1e30f
#define NBLK 512         // grid size = exactly 2 blocks/CU, fully resident
#define SCALE (1.0f / 131072.0f)   // 1 / (B * 2T)

__global__ __launch_bounds__(512, 4) void lcl_main(
    const float* __restrict__ mot, const float* __restrict__ aud,
    float* __restrict__ ws)
{
    __shared__ unsigned short sm[ROWS * SROW];
    __shared__ unsigned short sa[ROWS * SROW];
    __shared__ float invM[ROWS], invA[ROWS];   // inv row norms (of bf16 rows)
    __shared__ float redL[8], redC[8];

    const int tid  = threadIdx.x;
    const int lane = tid & 63;
    const int wv   = tid >> 6;     // 0..7
    const int g32  = tid >> 5;     // 0..15 staging group
    const int l32  = tid & 31;

    // XCD-aware bijective swizzle (512 % 8 == 0): same-XCD blocks are
    // t-adjacent within the same batch -> halo rows hit the same L2.
    const int lin = blockIdx.x;                       // 0..511
    const int swz = (lin & 7) * (NBLK / 8) + (lin >> 3);
    const int by  = swz >> 5;                         // batch 0..15
    const int tg  = swz & 31;                         // t-group (NTILE*TILE t's)
    const int tbase = tg * (NTILE * TILE);
    const size_t base = (size_t)by * (T_DIM * D_DIM);

    // per-wave task: dir = wv>>2, mi = wv&3
    const int dir = wv >> 2;
    const int mi  = wv & 3;
    const unsigned short* q = dir ? sa : sm;
    const unsigned short* k = dir ? sm : sa;
    float* invKarr = dir ? invM : invA;        // this wave's k-tensor norms
    const float* invQarr = dir ? invA : invM;

    const int fr    = lane & 15;
    const int fch   = (lane >> 4) * 8;
    const int col16 = lane & 15;
    const int g     = lane >> 4;

    // ---- prologue: issue tile-0 loads (held in registers) ----
    float4 vm[6], va[6];
    {
        const size_t off = base + (size_t)(tbase - 16 + g32) * D_DIM + l32 * 4;
        const float* spm = mot + off;
        const float* spa = aud + off;
        #pragma unroll
        for (int i = 0; i < 6; ++i) {
            const bool ok = (unsigned)(tbase - 16 + g32 + 16 * i) < (unsigned)T_DIM;
            vm[i] = make_float4(0.f, 0.f, 0.f, 0.f);
            va[i] = vm[i];
            if (ok) {
                vm[i] = *reinterpret_cast<const float4*>(spm + (size_t)(16 * i) * D_DIM);
                va[i] = *reinterpret_cast<const float4*>(spa + (size_t)(16 * i) * D_DIM);
            }
        }
    }

    float lossW = 0.f, corrW = 0.f;

    #pragma unroll
    for (int tile = 0; tile < NTILE; ++tile) {
        const int t0 = tbase + tile * TILE;

        // ---- convert held registers -> bf16 -> LDS ----
        {
            unsigned short* dpm = sm + g32 * SROW + l32 * 4;
            unsigned short* dpa = sa + g32 * SROW + l32 * 4;
            #pragma unroll
            for (int i = 0; i < 6; ++i) {
                union { __hip_bfloat16 h[4]; uint2 u; } pm, pa;
                pm.h[0] = __float2bfloat16(vm[i].x);
                pm.h[1] = __float2bfloat16(vm[i].y);
                pm.h[2] = __float2bfloat16(vm[i].z);
                pm.h[3] = __float2bfloat16(vm[i].w);
                pa.h[0] = __float2bfloat16(va[i].x);
                pa.h[1] = __float2bfloat16(va[i].y);
                pa.h[2] = __float2bfloat16(va[i].z);
                pa.h[3] = __float2bfloat16(va[i].w);
                *reinterpret_cast<uint2*>(dpm + 16 * i * SROW) = pm.u;
                *reinterpret_cast<uint2*>(dpa + 16 * i * SROW) = pa.u;
            }
        }
        __syncthreads();   // barrier A: staging visible

        // ---- issue NEXT tile's loads; latency hides under MFMA+reduce ----
        if (tile + 1 < NTILE) {
            const int tn = t0 + TILE;
            const size_t off = base + (size_t)(tn - 16 + g32) * D_DIM + l32 * 4;
            const float* spm = mot + off;
            const float* spa = aud + off;
            #pragma unroll
            for (int i = 0; i < 6; ++i) {
                const bool ok = (unsigned)(tn - 16 + g32 + 16 * i) < (unsigned)T_DIM;
                vm[i] = make_float4(0.f, 0.f, 0.f, 0.f);
                va[i] = vm[i];
                if (ok) {
                    vm[i] = *reinterpret_cast<const float4*>(spm + (size_t)(16 * i) * D_DIM);
                    va[i] = *reinterpret_cast<const float4*>(spa + (size_t)(16 * i) * D_DIM);
                }
            }
        }

        // ---- SWAPPED MFMA: A = k rows, B = q rows -> C[row=k_jj][col=q_t]
        // Norm self-Grams reuse already-loaded A fragments (0 extra ds_reads).
        f32x4 acc0 = {0.f,0.f,0.f,0.f}, acc1 = acc0, acc2 = acc0;
        f32x4 n0 = acc0, n1 = acc0;
        const unsigned short* qrow = q + (16 * (mi + 1) + fr) * SROW + fch;
        const unsigned short* k0   = k + ((mi + 0) * 16 + fr) * SROW + fch;
        const unsigned short* k1   = k + ((mi + 1) * 16 + fr) * SROW + fch;
        const unsigned short* k2   = k + ((mi + 2) * 16 + fr) * SROW + fch;
        #pragma unroll
        for (int ks = 0; ks < 4; ++ks) {
            bf16x8 bq = *reinterpret_cast<const bf16x8*>(qrow + ks * 32);
            bf16x8 a0 = *reinterpret_cast<const bf16x8*>(k0   + ks * 32);
            bf16x8 a1 = *reinterpret_cast<const bf16x8*>(k1   + ks * 32);
            bf16x8 a2 = *reinterpret_cast<const bf16x8*>(k2   + ks * 32);
            acc0 = __builtin_amdgcn_mfma_f32_16x16x32_bf16(a0, bq, acc0, 0, 0, 0);
            acc1 = __builtin_amdgcn_mfma_f32_16x16x32_bf16(a1, bq, acc1, 0, 0, 0);
            acc2 = __builtin_amdgcn_mfma_f32_16x16x32_bf16(a2, bq, acc2, 0, 0, 0);
            n0   = __builtin_amdgcn_mfma_f32_16x16x32_bf16(a0, a0, n0, 0, 0, 0);
            if (mi >= 2)
                n1 = __builtin_amdgcn_mfma_f32_16x16x32_bf16(a2, a2, n1, 0, 0, 0);
        }

        // ---- Gram diagonals -> inv norms (blocks 0..5 covered, both tensors)
        if ((col16 >> 2) == g) {
            const int r = col16 & 3;
            invKarr[16 * mi + col16] = 1.0f / fmaxf(sqrtf(n0[r]), 1e-12f);
            if (mi >= 2)
                invKarr[16 * (mi + 2) + col16] = 1.0f / fmaxf(sqrtf(n1[r]), 1e-12f);
        }
        __syncthreads();   // barrier B: norms visible; MFMA LDS reads done

        // ---- band reduction: lane owns q-row t=col16; regs hold k values ----
        const float scq10 = 10.0f * invQarr[16 * (mi + 1) + col16];
        const f32x4 sck0 = *reinterpret_cast<const f32x4*>(&invKarr[16 * (mi + 0) + 4 * g]);
        const f32x4 sck1 = *reinterpret_cast<const f32x4*>(&invKarr[16 * (mi + 1) + 4 * g]);
        const f32x4 sck2 = *reinterpret_cast<const f32x4*>(&invKarr[16 * (mi + 2) + 4 * g]);

        const int jbase  = t0 - 16 + 16 * mi + 4 * g;   // + 16b + r = key idx
        const int kkbase = 4 * g - col16;               // + 16b + r = kk

        float lv[12], pv[12];
        float mx = NEGV, mxp = NEGV;
        #pragma unroll
        for (int bb = 0; bb < 3; ++bb) {
            const f32x4 acc = (bb == 0) ? acc0 : ((bb == 1) ? acc1 : acc2);
            const f32x4 sck = (bb == 0) ? sck0 : ((bb == 1) ? sck1 : sck2);
            #pragma unroll
            for (int r = 0; r < 4; ++r) {
                const int kk = kkbase + 16 * bb + r;
                const int jg = jbase  + 16 * bb + r;
                const bool ok = ((unsigned)kk < 32u) && ((unsigned)jg < (unsigned)T_DIM);
                const float li = ok ? acc[r] * (scq10 * sck[r]) : NEGV;
                const float pi = ((unsigned)(kk - 12) < 8u) ? li : NEGV;
                lv[bb * 4 + r] = li;
                pv[bb * 4 + r] = pi;
                mx  = fmaxf(mx,  li);
                mxp = fmaxf(mxp, pi);
            }
        }
        mx  = fmaxf(mx,  __shfl_xor(mx,  16));
        mx  = fmaxf(mx,  __shfl_xor(mx,  32));
        mxp = fmaxf(mxp, __shfl_xor(mxp, 16));
        mxp = fmaxf(mxp, __shfl_xor(mxp, 32));

        float s = 0.f, sp = 0.f;
        #pragma unroll
        for (int i = 0; i < 12; ++i) {
            s  += __expf(lv[i] - mx);    // NEGV entries -> 0
            sp += __expf(pv[i] - mxp);
        }
        s  += __shfl_xor(s,  16);  s  += __shfl_xor(s,  32);
        sp += __shfl_xor(sp, 16);  sp += __shfl_xor(sp, 32);

        if (g == 0) {                    // lanes 0..15: one q-row each
            lossW += (mx + __logf(s)) - (mxp + __logf(sp));
            corrW += (mxp >= mx) ? 1.0f : 0.0f;
        }
        // no end-of-tile barrier needed: next convert touches only sm/sa,
        // whose readers (MFMA) all completed before barrier B; the band
        // reduce reads only invM/invA, next written after the next barrier A.
    }

    // ---- block reduction -> per-block partials in ws (no atomics) ----
    #pragma unroll
    for (int m = 32; m; m >>= 1) {
        lossW += __shfl_xor(lossW, m);
        corrW += __shfl_xor(corrW, m);
    }
    if (lane == 0) { redL[wv] = lossW; redC[wv] = corrW; }
    __syncthreads();
    if (tid == 0) {
        float L = 0.f, C = 0.f;
        #pragma unroll
        for (int i = 0; i < 8; ++i) { L += redL[i]; C += redC[i]; }
        ws[2 * swz]     = L;
        ws[2 * swz + 1] = C;
    }
}

__global__ __launch_bounds__(256) void lcl_final(
    const float* __restrict__ ws, float* __restrict__ out)
{
    const int tid = threadIdx.x;
    float L = 0.f, C = 0.f;
    #pragma unroll
    for (int i = 0; i < 2; ++i) {
        const int idx = tid + i * 256;
        L += ws[2 * idx];
        C += ws[2 * idx + 1];
    }
    #pragma unroll
    for (int m = 32; m; m >>= 1) { L += __shfl_xor(L, m); C += __shfl_xor(C, m); }
    __shared__ float rl[4], rc[4];
    if ((tid & 63) == 0) { rl[tid >> 6] = L; rc[tid >> 6] = C; }
    __syncthreads();
    if (tid == 0) {
        out[0] = (rl[0] + rl[1] + rl[2] + rl[3]) * SCALE;
        out[1] = (rc[0] + rc[1] + rc[2] + rc[3]) * SCALE;
    }
}

extern "C" void kernel_launch(void* const* d_in, const int* in_sizes, int n_in,
                              void* d_out, int out_size, void* d_ws, size_t ws_size,
                              hipStream_t stream) {
    const float* mot = (const float*)d_in[0];
    const float* aud = (const float*)d_in[1];
    float* out = (float*)d_out;
    float* ws  = (float*)d_ws;   // 512 blocks x 2 floats, fully overwritten

    lcl_main<<<NBLK, 512, 0, stream>>>(mot, aud, ws);
    lcl_final<<<1, 256, 0, stream>>>(ws, out);
}

// Round 10
// 23.382 us; speedup vs baseline: 2.3791x; 1.0358x over previous
//
#include <hip/hip_runtime.h>
#include <hip/hip_bf16.h>

typedef __attribute__((ext_vector_type(8))) short bf16x8;
typedef __attribute__((ext_vector_type(4))) float f32x4;

#define T_DIM 4096
#define B_DIM 16
#define D_DIM 128
#define TILE 64
#define NTILE 2          // tiles per block (pipelined)
#define ROWS 96          // staged rows per tile: t0-16 .. t0+79
#define SROW 136         // bf16 units per row (272 B, 16B-aligned)
#define NEGV -1e30f
#define NBLK 512         // grid = 2 blocks/CU, fully resident
#define SCALE (1.0f / 131072.0f)   // 1 / (B * 2T)

__global__ __launch_bounds__(512, 4) void lcl_main(
    const float* __restrict__ mot, const float* __restrict__ aud,
    float* __restrict__ ws)
{
    __shared__ unsigned short sm[ROWS * SROW];
    __shared__ unsigned short sa[ROWS * SROW];
    __shared__ float invM[ROWS], invA[ROWS];   // inv row norms (of bf16 rows)
    __shared__ float redL[8], redC[8];

    const int tid  = threadIdx.x;
    const int lane = tid & 63;
    const int wv   = tid >> 6;     // 0..7
    const int g32  = tid >> 5;     // 0..15 staging group
    const int l32  = tid & 31;

    // XCD-aware bijective swizzle (512 % 8 == 0): same-XCD blocks are
    // t-adjacent within the same batch -> halo rows hit the same L2.
    const int lin = blockIdx.x;                       // 0..511
    const int swz = (lin & 7) * (NBLK / 8) + (lin >> 3);
    const int by  = swz >> 5;                         // batch 0..15
    const int tg  = swz & 31;                         // t-group
    const int tbase = tg * (NTILE * TILE);
    const size_t base = (size_t)by * (T_DIM * D_DIM);

    // per-wave task: dir = wv>>2, mi = wv&3
    const int dir = wv >> 2;
    const int mi  = wv & 3;
    const unsigned short* q = dir ? sa : sm;
    const unsigned short* k = dir ? sm : sa;
    float* invKarr = dir ? invM : invA;        // this wave's k-tensor norms
    const float* invQarr = dir ? invA : invM;

    const int fr    = lane & 15;
    const int fch   = (lane >> 4) * 8;
    const int col16 = lane & 15;
    const int g     = lane >> 4;

    // ---- prologue: issue tile-0 loads (held in registers) ----
    float4 vm[6], va[6];
    {
        const size_t off = base + (size_t)(tbase - 16 + g32) * D_DIM + l32 * 4;
        const float* spm = mot + off;
        const float* spa = aud + off;
        #pragma unroll
        for (int i = 0; i < 6; ++i) {
            const bool ok = (unsigned)(tbase - 16 + g32 + 16 * i) < (unsigned)T_DIM;
            vm[i] = make_float4(0.f, 0.f, 0.f, 0.f);
            va[i] = vm[i];
            if (ok) {
                vm[i] = *reinterpret_cast<const float4*>(spm + (size_t)(16 * i) * D_DIM);
                va[i] = *reinterpret_cast<const float4*>(spa + (size_t)(16 * i) * D_DIM);
            }
        }
    }

    float lossW = 0.f, corrW = 0.f;

    #pragma unroll
    for (int tile = 0; tile < NTILE; ++tile) {
        const int t0 = tbase + tile * TILE;

        // ---- convert held registers -> bf16 -> LDS ----
        {
            unsigned short* dpm = sm + g32 * SROW + l32 * 4;
            unsigned short* dpa = sa + g32 * SROW + l32 * 4;
            #pragma unroll
            for (int i = 0; i < 6; ++i) {
                union { __hip_bfloat16 h[4]; uint2 u; } pm, pa;
                pm.h[0] = __float2bfloat16(vm[i].x);
                pm.h[1] = __float2bfloat16(vm[i].y);
                pm.h[2] = __float2bfloat16(vm[i].z);
                pm.h[3] = __float2bfloat16(vm[i].w);
                pa.h[0] = __float2bfloat16(va[i].x);
                pa.h[1] = __float2bfloat16(va[i].y);
                pa.h[2] = __float2bfloat16(va[i].z);
                pa.h[3] = __float2bfloat16(va[i].w);
                *reinterpret_cast<uint2*>(dpm + 16 * i * SROW) = pm.u;
                *reinterpret_cast<uint2*>(dpa + 16 * i * SROW) = pa.u;
            }
        }

        // ---- issue NEXT tile's loads (vm/va now dead); extra latency cover ----
        if (tile + 1 < NTILE) {
            const int tn = t0 + TILE;
            const size_t off = base + (size_t)(tn - 16 + g32) * D_DIM + l32 * 4;
            const float* spm = mot + off;
            const float* spa = aud + off;
            #pragma unroll
            for (int i = 0; i < 6; ++i) {
                const bool ok = (unsigned)(tn - 16 + g32 + 16 * i) < (unsigned)T_DIM;
                vm[i] = make_float4(0.f, 0.f, 0.f, 0.f);
                va[i] = vm[i];
                if (ok) {
                    vm[i] = *reinterpret_cast<const float4*>(spm + (size_t)(16 * i) * D_DIM);
                    va[i] = *reinterpret_cast<const float4*>(spa + (size_t)(16 * i) * D_DIM);
                }
            }
        }
        __syncthreads();   // barrier A: staging visible

        // ---- SWAPPED MFMA: A = k rows, B = q rows -> C[row=k_jj][col=q_t]
        // Norm self-Grams reuse already-loaded A fragments (0 extra ds_reads).
        f32x4 acc0 = {0.f,0.f,0.f,0.f}, acc1 = acc0, acc2 = acc0;
        f32x4 n0 = acc0, n1 = acc0;
        const unsigned short* qrow = q + (16 * (mi + 1) + fr) * SROW + fch;
        const unsigned short* k0   = k + ((mi + 0) * 16 + fr) * SROW + fch;
        const unsigned short* k1   = k + ((mi + 1) * 16 + fr) * SROW + fch;
        const unsigned short* k2   = k + ((mi + 2) * 16 + fr) * SROW + fch;
        #pragma unroll
        for (int ks = 0; ks < 4; ++ks) {
            bf16x8 bq = *reinterpret_cast<const bf16x8*>(qrow + ks * 32);
            bf16x8 a0 = *reinterpret_cast<const bf16x8*>(k0   + ks * 32);
            bf16x8 a1 = *reinterpret_cast<const bf16x8*>(k1   + ks * 32);
            bf16x8 a2 = *reinterpret_cast<const bf16x8*>(k2   + ks * 32);
            acc0 = __builtin_amdgcn_mfma_f32_16x16x32_bf16(a0, bq, acc0, 0, 0, 0);
            acc1 = __builtin_amdgcn_mfma_f32_16x16x32_bf16(a1, bq, acc1, 0, 0, 0);
            acc2 = __builtin_amdgcn_mfma_f32_16x16x32_bf16(a2, bq, acc2, 0, 0, 0);
            n0   = __builtin_amdgcn_mfma_f32_16x16x32_bf16(a0, a0, n0, 0, 0, 0);
            if (mi >= 2)
                n1 = __builtin_amdgcn_mfma_f32_16x16x32_bf16(a2, a2, n1, 0, 0, 0);
        }

        // ---- Gram diagonals -> inv norms (blocks 0..5 covered, both tensors)
        if ((col16 >> 2) == g) {
            const int r = col16 & 3;
            invKarr[16 * mi + col16] = 1.0f / fmaxf(sqrtf(n0[r]), 1e-12f);
            if (mi >= 2)
                invKarr[16 * (mi + 2) + col16] = 1.0f / fmaxf(sqrtf(n1[r]), 1e-12f);
        }
        __syncthreads();   // barrier B: norms visible; MFMA LDS reads done

        // ---- band reduction: lane owns q-row t=col16; regs hold k values ----
        // Single shared max: lse_all = mx + log(s); lse_pos = mx + log(sp)
        // (exact algebra; no underflow, logit span <= 20). Loss = log(s/sp).
        // mxp kept only for the correct-count comparison.
        const float scq10 = 10.0f * invQarr[16 * (mi + 1) + col16];
        const f32x4 sck0 = *reinterpret_cast<const f32x4*>(&invKarr[16 * (mi + 0) + 4 * g]);
        const f32x4 sck1 = *reinterpret_cast<const f32x4*>(&invKarr[16 * (mi + 1) + 4 * g]);
        const f32x4 sck2 = *reinterpret_cast<const f32x4*>(&invKarr[16 * (mi + 2) + 4 * g]);

        const int jbase  = t0 - 16 + 16 * mi + 4 * g;   // + 16b + r = key idx
        const int kkbase = 4 * g - col16;               // + 16b + r = kk

        float lv[12];
        bool  pm[12];
        float mx = NEGV, mxp = NEGV;
        #pragma unroll
        for (int bb = 0; bb < 3; ++bb) {
            const f32x4 acc = (bb == 0) ? acc0 : ((bb == 1) ? acc1 : acc2);
            const f32x4 sck = (bb == 0) ? sck0 : ((bb == 1) ? sck1 : sck2);
            #pragma unroll
            for (int r = 0; r < 4; ++r) {
                const int kk = kkbase + 16 * bb + r;
                const int jg = jbase  + 16 * bb + r;
                const bool ok = ((unsigned)kk < 32u) && ((unsigned)jg < (unsigned)T_DIM);
                const float li = ok ? acc[r] * (scq10 * sck[r]) : NEGV;
                const bool  pi = ((unsigned)(kk - 12) < 8u);   // li=NEGV if !ok
                lv[bb * 4 + r] = li;
                pm[bb * 4 + r] = pi;
                mx  = fmaxf(mx, li);
                mxp = pi ? fmaxf(mxp, li) : mxp;
            }
        }
        mx  = fmaxf(mx,  __shfl_xor(mx,  16));
        mx  = fmaxf(mx,  __shfl_xor(mx,  32));
        mxp = fmaxf(mxp, __shfl_xor(mxp, 16));
        mxp = fmaxf(mxp, __shfl_xor(mxp, 32));

        float s = 0.f, sp = 0.f;
        #pragma unroll
        for (int i = 0; i < 12; ++i) {
            const float e = __expf(lv[i] - mx);   // NEGV entries -> 0
            s  += e;
            sp += pm[i] ? e : 0.f;
        }
        s  += __shfl_xor(s,  16);  s  += __shfl_xor(s,  32);
        sp += __shfl_xor(sp, 16);  sp += __shfl_xor(sp, 32);

        if (g == 0) {                    // lanes 0..15: one q-row each
            lossW += __logf(s / sp);
            corrW += (mxp >= mx) ? 1.0f : 0.0f;
        }
        // no end-of-tile barrier needed: next convert writes sm/sa whose
        // readers (MFMA) completed before barrier B; band reduce reads only
        // invM/invA, next overwritten after the next barrier A.
    }

    // ---- block reduction -> per-block partials in ws (no atomics) ----
    #pragma unroll
    for (int m = 32; m; m >>= 1) {
        lossW += __shfl_xor(lossW, m);
        corrW += __shfl_xor(corrW, m);
    }
    if (lane == 0) { redL[wv] = lossW; redC[wv] = corrW; }
    __syncthreads();
    if (tid == 0) {
        float L = 0.f, C = 0.f;
        #pragma unroll
        for (int i = 0; i < 8; ++i) { L += redL[i]; C += redC[i]; }
        ws[2 * swz]     = L;
        ws[2 * swz + 1] = C;
    }
}

__global__ __launch_bounds__(256) void lcl_final(
    const float* __restrict__ ws, float* __restrict__ out)
{
    const int tid = threadIdx.x;
    const float2* w2 = reinterpret_cast<const float2*>(ws);
    float L = 0.f, C = 0.f;
    #pragma unroll
    for (int i = 0; i < 2; ++i) {
        const float2 v = w2[tid + i * 256];
        L += v.x;
        C += v.y;
    }
    #pragma unroll
    for (int m = 32; m; m >>= 1) { L += __shfl_xor(L, m); C += __shfl_xor(C, m); }
    __shared__ float rl[4], rc[4];
    if ((tid & 63) == 0) { rl[tid >> 6] = L; rc[tid >> 6] = C; }
    __syncthreads();
    if (tid == 0) {
        out[0] = (rl[0] + rl[1] + rl[2] + rl[3]) * SCALE;
        out[1] = (rc[0] + rc[1] + rc[2] + rc[3]) * SCALE;
    }
}

extern "C" void kernel_launch(void* const* d_in, const int* in_sizes, int n_in,
                              void* d_out, int out_size, void* d_ws, size_t ws_size,
                              hipStream_t stream) {
    const float* mot = (const float*)d_in[0];
    const float* aud = (const float*)d_in[1];
    float* out = (float*)d_out;
    float* ws  = (float*)d_ws;   // 512 blocks x 2 floats, fully overwritten

    lcl_main<<<NBLK, 512, 0, stream>>>(mot, aud, ws);
    lcl_final<<<1, 256, 0, stream>>>(ws, out);
}